// Round 2
// baseline (432.928 us; speedup 1.0000x reference)
//
#include <hip/hip_runtime.h>
#include <math.h>

// BioMechFeatures: B x 12 x 256 float32 inputs (foot, shank, thigh) -> B x 44 float32.
// One block of 256 threads per batch element.

__device__ __forceinline__ float wsum(float v){
  v += __shfl_xor(v,32); v += __shfl_xor(v,16); v += __shfl_xor(v,8);
  v += __shfl_xor(v,4);  v += __shfl_xor(v,2);  v += __shfl_xor(v,1);
  return v;
}
__device__ __forceinline__ float wmaxr(float v){
  v = fmaxf(v, __shfl_xor(v,32)); v = fmaxf(v, __shfl_xor(v,16));
  v = fmaxf(v, __shfl_xor(v,8));  v = fmaxf(v, __shfl_xor(v,4));
  v = fmaxf(v, __shfl_xor(v,2));  v = fmaxf(v, __shfl_xor(v,1));
  return v;
}
__device__ __forceinline__ float cmb4s(const volatile float* r){ return (r[0]+r[1])+(r[2]+r[3]); }
__device__ __forceinline__ float cmb4m(const volatile float* r){ return fmaxf(fmaxf(r[0],r[1]),fmaxf(r[2],r[3])); }
__device__ __forceinline__ float clampf(float v, float lo, float hi){ return fminf(fmaxf(v, lo), hi); }

__global__ __launch_bounds__(256) void biomech_kernel(
    const float* __restrict__ foot, const float* __restrict__ shank,
    const float* __restrict__ thigh, float* __restrict__ out)
{
  const int b    = blockIdx.x;
  const int t    = threadIdx.x;        // 0..255
  const int lane = t & 63;
  const int wv   = t >> 6;             // 0..3

  __shared__ float s_fz[2][256];
  __shared__ float s_sz[2][256];
  __shared__ float s_e[2][128];
  __shared__ float s_o[2][128];
  __shared__ float s_red[20][4];
  __shared__ float s_feat[44];

  const float* fp = foot  + (size_t)b * 3072;
  const float* sp = shank + (size_t)b * 3072;
  const float* tp = thigh + (size_t)b * 3072;

  // ---------------- Phase A: load z-channels, first-pass reductions ----------
  float xl = fp[2*256 + t];   // foot z lt (ch 2)
  float xr = fp[8*256 + t];   // foot z rt (ch 8)
  float yl = sp[2*256 + t];   // shank z lt
  float yr = sp[8*256 + t];   // shank z rt
  s_fz[0][t] = xl; s_fz[1][t] = xr;
  s_sz[0][t] = yl; s_sz[1][t] = yr;

  float axl = fabsf(xl), axr = fabsf(xr), ayl = fabsf(yl), ayr = fabsf(yr);

  float qa[18];
  qa[0]  = wmaxr(axl);               qa[1]  = wmaxr(axr);
  qa[2]  = wsum(xl);                 qa[3]  = wsum(xr);
  qa[4]  = wsum(xl*xl);              qa[5]  = wsum(xr*xr);
  qa[6]  = wsum(t<128 ? axl : 0.f);  qa[7]  = wsum(t<128 ? 0.f : axl);
  qa[8]  = wsum(t<128 ? axr : 0.f);  qa[9]  = wsum(t<128 ? 0.f : axr);
  qa[10] = wsum((t&1) ? -xl : xl);   qa[11] = wsum((t&1) ? -xr : xr);
  qa[12] = wmaxr(ayl);               qa[13] = wmaxr(ayr);
  qa[14] = wsum(yl);                 qa[15] = wsum(yr);
  qa[16] = wsum(yl*yl);              qa[17] = wsum(yr*yr);
  if (lane == 0) {
    #pragma unroll
    for (int i = 0; i < 18; ++i) s_red[i][wv] = qa[i];
  }
  __syncthreads();   // also makes s_fz / s_sz visible

  float pk_l  = cmb4m(s_red[0]);  float pk_r  = cmb4m(s_red[1]);
  float sum_l = cmb4s(s_red[2]);  float sum_r = cmb4s(s_red[3]);
  float sq_l  = cmb4s(s_red[4]);  float sq_r  = cmb4s(s_red[5]);
  float h1l   = cmb4s(s_red[6]);  float h2l   = cmb4s(s_red[7]);
  float h1r   = cmb4s(s_red[8]);  float h2r   = cmb4s(s_red[9]);
  float alt_l = cmb4s(s_red[10]); float alt_r = cmb4s(s_red[11]);
  float spk_l = cmb4m(s_red[12]); float spk_r = cmb4m(s_red[13]);
  float ssum_l= cmb4s(s_red[14]); float ssum_r= cmb4s(s_red[15]);
  float ssq_l = cmb4s(s_red[16]); float ssq_r = cmb4s(s_red[17]);

  // ---------------- Phase B: second pass (moments, dur, zcr, vib) + e/o -----
  float mu_l = sum_l * (1.f/256.f), mu_r = sum_r * (1.f/256.f);
  float var_fl = fmaxf((sq_l - 256.f*mu_l*mu_l) * (1.f/255.f), 0.f);
  float var_fr = fmaxf((sq_r - 256.f*mu_r*mu_r) * (1.f/255.f), 0.f);
  float std_l = sqrtf(var_fl), std_r = sqrtf(var_fr);
  float inv_l = 1.f / fmaxf(std_l, 1e-6f), inv_r = 1.f / fmaxf(std_r, 1e-6f);

  float pl = (xl - mu_l) * inv_l, pr = (xr - mu_r) * inv_r;
  float pl2 = pl*pl, pr2 = pr*pr;

  float xln = (t < 255) ? s_fz[0][t+1] : xl;
  float xrn = (t < 255) ? s_fz[1][t+1] : xr;
  float yln = (t < 255) ? s_sz[0][t+1] : yl;
  float yrn = (t < 255) ? s_sz[1][t+1] : yr;
  float crl = (t < 255 && ((xl < 0.f) != (xln < 0.f))) ? 1.f : 0.f;
  float crr = (t < 255 && ((xr < 0.f) != (xrn < 0.f))) ? 1.f : 0.f;
  float vbl = (t < 255) ? fabsf(yln - yl) : 0.f;
  float vbr = (t < 255) ? fabsf(yrn - yr) : 0.f;
  float dl  = (axl >= 0.3f * pk_l) ? 1.f : 0.f;
  float dr  = (axr >= 0.3f * pk_r) ? 1.f : 0.f;

  { // fold conjugate-symmetric pairs for the DFT: e[n]=x[n]+x[256-n], o[n]=x[n]-x[256-n]
    int rr = t >> 7, n = t & 127;
    if (n != 0) {
      float a = s_fz[rr][n], c = s_fz[rr][256 - n];
      s_e[rr][n] = a + c; s_o[rr][n] = a - c;
    }
  }

  float qb[10];
  qb[0] = wsum(pl2*pl);  qb[1] = wsum(pl2*pl2);
  qb[2] = wsum(pr2*pr);  qb[3] = wsum(pr2*pr2);
  qb[4] = wsum(dl);      qb[5] = wsum(dr);
  qb[6] = wsum(crl);     qb[7] = wsum(crr);
  qb[8] = wsum(vbl);     qb[9] = wsum(vbr);
  __syncthreads();                       // protect scratch WAR
  if (lane == 0) {
    #pragma unroll
    for (int i = 0; i < 10; ++i) s_red[i][wv] = qb[i];
  }
  __syncthreads();

  float p3l = cmb4s(s_red[0]), p4l = cmb4s(s_red[1]);
  float p3r = cmb4s(s_red[2]), p4r = cmb4s(s_red[3]);
  float dcl = cmb4s(s_red[4]), dcr = cmb4s(s_red[5]);
  float zcl = cmb4s(s_red[6]), zcr_ = cmb4s(s_red[7]);
  float vibl = cmb4s(s_red[8]), vibr = cmb4s(s_red[9]);

  // ---------------- Phase C: 6 gyro groups (3 channels each) ----------------
  float gvar[6], gpk[6];
  for (int g = 0; g < 6; ++g) {
    const float* base = (g < 2) ? fp : (g < 4) ? sp : tp;
    const float* src  = base + ((g & 1) ? 9*256 : 3*256);
    float v0 = src[t], v1 = src[256 + t], v2 = src[512 + t];
    float m  = fmaxf(fmaxf(fabsf(v0), fabsf(v1)), fabsf(v2));
    float qg[7];
    qg[0] = wsum(v0); qg[1] = wsum(v0*v0);
    qg[2] = wsum(v1); qg[3] = wsum(v1*v1);
    qg[4] = wsum(v2); qg[5] = wsum(v2*v2);
    qg[6] = wmaxr(m);
    __syncthreads();
    if (lane == 0) {
      #pragma unroll
      for (int i = 0; i < 7; ++i) s_red[i][wv] = qg[i];
    }
    __syncthreads();
    float s0 = cmb4s(s_red[0]), q0 = cmb4s(s_red[1]);
    float s1 = cmb4s(s_red[2]), q1 = cmb4s(s_red[3]);
    float s2 = cmb4s(s_red[4]), q2 = cmb4s(s_red[5]);
    gpk[g]  = cmb4m(s_red[6]);
    float vv = (q0 - s0*s0*(1.f/256.f)) + (q1 - s1*s1*(1.f/256.f)) + (q2 - s2*s2*(1.f/256.f));
    gvar[g] = vv * (1.f/255.f);
  }

  // ---------------- Phase D: DFT power spectrum (bins 0..127 per row) -------
  // 256 threads = 2 rows x 128 bins. Bin 128 handled via alternating sum.
  const int rr = t >> 7;       // wave-uniform: waves 0,1 -> row 0; waves 2,3 -> row 1
  const int k  = t & 127;
  float th = (float)k * (6.283185307179586f / 256.f);
  float c1, s1w;
  __sincosf(th, &s1w, &c1);
  float x0 = s_fz[rr][0], x128 = s_fz[rr][128];
  float accc = x0 + ((k & 1) ? -x128 : x128);
  float accs = 0.f;
  float c = c1, s = s1w;
  #pragma unroll 4
  for (int n = 1; n < 128; ++n) {
    float e = s_e[rr][n], o = s_o[rr][n];   // wave-uniform broadcast reads
    accc = fmaf(e, c, accc);
    accs = fmaf(o, s, accs);
    float cn = fmaf(c, c1, -(s * s1w));     // rotate by th (angle-addition)
    s = fmaf(s, c1, c * s1w);
    c = cn;
  }
  float P = accc*accc + accs*accs;
  float qd0 = wsum(P);
  float qd1 = wsum((k >= 60) ? P : 0.f);
  float qd2 = wsum((float)k * P);
  __syncthreads();
  if (lane == 0) { s_red[0][wv] = qd0; s_red[1][wv] = qd1; s_red[2][wv] = qd2; }
  __syncthreads();

  float P128_l = alt_l * alt_l, P128_r = alt_r * alt_r;
  float tot_l = s_red[0][0] + s_red[0][1] + P128_l;
  float tot_r = s_red[0][2] + s_red[0][3] + P128_r;
  float hf_l  = (s_red[1][0] + s_red[1][1] + P128_l) / (tot_l + 1e-6f);
  float hf_r  = (s_red[1][2] + s_red[1][3] + P128_r) / (tot_r + 1e-6f);
  float cw_l  = s_red[2][0] + s_red[2][1] + 128.f * P128_l;
  float cw_r  = s_red[2][2] + s_red[2][3] + 128.f * P128_r;
  float sc_l  = cw_l / (tot_l + 1e-6f) * (1.f/129.f);
  float sc_r  = cw_r / (tot_r + 1e-6f) * (1.f/129.f);

  // ---------------- Epilogue: assemble 44 features --------------------------
  if (t == 0) {
    float var_sl = fmaxf((ssq_l - ssum_l*ssum_l*(1.f/256.f)) * (1.f/255.f), 0.f);
    float var_sr = fmaxf((ssq_r - ssum_r*ssum_r*(1.f/256.f)) * (1.f/255.f), 0.f);
    float frms_l = sqrtf(sq_l  * (1.f/256.f)), frms_r = sqrtf(sq_r  * (1.f/256.f));
    float srms_l = sqrtf(ssq_l * (1.f/256.f)), srms_r = sqrtf(ssq_r * (1.f/256.f));
    float fgv_l = log1pf(gvar[0]), fgv_r = log1pf(gvar[1]);
    float sgv_l = log1pf(gvar[2]), sgv_r = log1pf(gvar[3]);
    float tgv_l = log1pf(gvar[4]), tgv_r = log1pf(gvar[5]);

    s_feat[0]  = pk_l;  s_feat[1]  = pk_r;
    s_feat[2]  = spk_l; s_feat[3]  = spk_r;
    s_feat[4]  = log1pf(pk_l / (spk_l + 1e-4f));
    s_feat[5]  = log1pf(pk_r / (spk_r + 1e-4f));
    s_feat[6]  = hf_l;  s_feat[7]  = hf_r;
    s_feat[8]  = std_l; s_feat[9]  = std_r;
    s_feat[10] = (h1l * (1.f/128.f)) / (h2l * (1.f/128.f) + 1e-6f);
    s_feat[11] = (h1r * (1.f/128.f)) / (h2r * (1.f/128.f) + 1e-6f);
    s_feat[12] = vibl * (1.f/255.f);
    s_feat[13] = vibr * (1.f/255.f);
    s_feat[14] = log1pf(var_fl / (var_sl + 1e-4f));
    s_feat[15] = log1pf(var_fr / (var_sr + 1e-4f));
    s_feat[16] = sc_l;  s_feat[17] = sc_r;
    s_feat[18] = dcl * (1.f/256.f);
    s_feat[19] = dcr * (1.f/256.f);
    s_feat[20] = fgv_l; s_feat[21] = fgv_r;
    s_feat[22] = gpk[0]; s_feat[23] = gpk[1];
    s_feat[24] = sgv_l; s_feat[25] = sgv_r;
    s_feat[26] = gpk[2]; s_feat[27] = gpk[3];
    s_feat[28] = tgv_l; s_feat[29] = tgv_r;
    s_feat[30] = gpk[4]; s_feat[31] = gpk[5];
    s_feat[32] = fabsf(pk_l - spk_l);
    s_feat[33] = fabsf(pk_r - spk_r);
    s_feat[34] = fabsf(fgv_l - sgv_l);
    s_feat[35] = fabsf(fgv_r - sgv_r);
    s_feat[36] = log1pf(srms_l / (frms_l + 1e-6f));
    s_feat[37] = log1pf(srms_r / (frms_r + 1e-6f));
    s_feat[38] = clampf(p4l * (1.f/256.f), -10.f, 30.f);
    s_feat[39] = clampf(p4r * (1.f/256.f), -10.f, 30.f);
    s_feat[40] = clampf(p3l * (1.f/256.f), -10.f, 10.f);
    s_feat[41] = clampf(p3r * (1.f/256.f), -10.f, 10.f);
    s_feat[42] = zcl  * (1.f/255.f);
    s_feat[43] = zcr_ * (1.f/255.f);
  }
  __syncthreads();
  if (t < 44) out[(size_t)b * 44 + t] = s_feat[t];
}

extern "C" void kernel_launch(void* const* d_in, const int* in_sizes, int n_in,
                              void* d_out, int out_size, void* d_ws, size_t ws_size,
                              hipStream_t stream) {
  const float* foot  = (const float*)d_in[0];
  const float* shank = (const float*)d_in[1];
  const float* thigh = (const float*)d_in[2];
  float* out = (float*)d_out;
  int B = in_sizes[0] / (12 * 256);
  biomech_kernel<<<dim3(B), dim3(256), 0, stream>>>(foot, shank, thigh, out);
}

// Round 3
// 91.820 us; speedup vs baseline: 4.7150x; 4.7150x over previous
//
#include <hip/hip_runtime.h>
#include <math.h>

// BioMechFeatures: B x 12 x 256 f32 (foot, shank, thigh) -> B x 44 f32.
// ONE WAVE per batch element (4 waves / 256-thread block, zero __syncthreads).
// Each lane holds 4 consecutive samples (float4); all reductions are wave shuffles.

__device__ __forceinline__ float wsum(float v){
  v += __shfl_xor(v,1); v += __shfl_xor(v,2); v += __shfl_xor(v,4);
  v += __shfl_xor(v,8); v += __shfl_xor(v,16); v += __shfl_xor(v,32);
  return v;
}
__device__ __forceinline__ float wmax(float v){
  v = fmaxf(v,__shfl_xor(v,1)); v = fmaxf(v,__shfl_xor(v,2)); v = fmaxf(v,__shfl_xor(v,4));
  v = fmaxf(v,__shfl_xor(v,8)); v = fmaxf(v,__shfl_xor(v,16)); v = fmaxf(v,__shfl_xor(v,32));
  return v;
}
__device__ __forceinline__ float sum4(float4 v){ return (v.x+v.y)+(v.z+v.w); }
__device__ __forceinline__ float dot4(float4 v){ return (v.x*v.x+v.y*v.y)+(v.z*v.z+v.w*v.w); }
__device__ __forceinline__ float amax4(float4 v){ return fmaxf(fmaxf(fabsf(v.x),fabsf(v.y)),fmaxf(fabsf(v.z),fabsf(v.w))); }
__device__ __forceinline__ float asum4(float4 v){ return (fabsf(v.x)+fabsf(v.y))+(fabsf(v.z)+fabsf(v.w)); }
__device__ __forceinline__ float clampf(float v,float lo,float hi){ return fminf(fmaxf(v,lo),hi); }

__global__ __launch_bounds__(256,4) void biomech_kernel(
    const float* __restrict__ foot, const float* __restrict__ shank,
    const float* __restrict__ thigh, float* __restrict__ out, int B)
{
  const int lane = threadIdx.x & 63;
  const int wv   = threadIdx.x >> 6;
  const int b    = blockIdx.x*4 + wv;
  if (b >= B) return;

  // per-wave e/o staging for the DFT: 4 arrays of 128 floats
  __shared__ float sEO[4][4][128];
  float* sE0 = sEO[wv][0]; float* sO0 = sEO[wv][1];
  float* sE1 = sEO[wv][2]; float* sO1 = sEO[wv][3];

  const float* fp = foot  + (size_t)b*3072;
  const float* sp = shank + (size_t)b*3072;
  const float* tp = thigh + (size_t)b*3072;

  // ---- z channels: ch2 (lt) / ch8 (rt); lane holds samples 4*lane..4*lane+3
  float4 xl = ((const float4*)(fp+ 512))[lane];
  float4 xr = ((const float4*)(fp+2048))[lane];
  float4 yl = ((const float4*)(sp+ 512))[lane];
  float4 yr = ((const float4*)(sp+2048))[lane];

  // ---- first-pass wave reductions
  float pk_l  = wmax(amax4(xl)), pk_r  = wmax(amax4(xr));
  float spk_l = wmax(amax4(yl)), spk_r = wmax(amax4(yr));
  float sum_l = wsum(sum4(xl)),  sum_r = wsum(sum4(xr));
  float sq_l  = wsum(dot4(xl)),  sq_r  = wsum(dot4(xr));
  float ssum_l= wsum(sum4(yl)),  ssum_r= wsum(sum4(yr));
  float ssq_l = wsum(dot4(yl)),  ssq_r = wsum(dot4(yr));
  float al = asum4(xl), ar = asum4(xr);
  float h1l = wsum(lane<32 ? al : 0.f), h2l = wsum(lane<32 ? 0.f : al);
  float h1r = wsum(lane<32 ? ar : 0.f), h2r = wsum(lane<32 ? 0.f : ar);
  float alt_l = wsum((xl.x - xl.y) + (xl.z - xl.w));   // sum of (-1)^n x[n]
  float alt_r = wsum((xr.x - xr.y) + (xr.z - xr.w));

  // ---- second pass (registers only)
  float mu_l = sum_l*(1.f/256.f), mu_r = sum_r*(1.f/256.f);
  float var_fl = fmaxf((sq_l - 256.f*mu_l*mu_l)*(1.f/255.f), 0.f);
  float var_fr = fmaxf((sq_r - 256.f*mu_r*mu_r)*(1.f/255.f), 0.f);
  float std_l = sqrtf(var_fl), std_r = sqrtf(var_fr);
  float inv_l = 1.f/fmaxf(std_l,1e-6f), inv_r = 1.f/fmaxf(std_r,1e-6f);

  float p3l_c=0.f, p4l_c=0.f, p3r_c=0.f, p4r_c=0.f;
  {
    float p,p2;
    p=(xl.x-mu_l)*inv_l; p2=p*p; p3l_c+=p2*p; p4l_c+=p2*p2;
    p=(xl.y-mu_l)*inv_l; p2=p*p; p3l_c+=p2*p; p4l_c+=p2*p2;
    p=(xl.z-mu_l)*inv_l; p2=p*p; p3l_c+=p2*p; p4l_c+=p2*p2;
    p=(xl.w-mu_l)*inv_l; p2=p*p; p3l_c+=p2*p; p4l_c+=p2*p2;
    p=(xr.x-mu_r)*inv_r; p2=p*p; p3r_c+=p2*p; p4r_c+=p2*p2;
    p=(xr.y-mu_r)*inv_r; p2=p*p; p3r_c+=p2*p; p4r_c+=p2*p2;
    p=(xr.z-mu_r)*inv_r; p2=p*p; p3r_c+=p2*p; p4r_c+=p2*p2;
    p=(xr.w-mu_r)*inv_r; p2=p*p; p3r_c+=p2*p; p4r_c+=p2*p2;
  }
  float p3l = wsum(p3l_c), p4l = wsum(p4l_c);
  float p3r = wsum(p3r_c), p4r = wsum(p4r_c);

  float thr_l = 0.3f*pk_l, thr_r = 0.3f*pk_r;
  float dl_c = (fabsf(xl.x)>=thr_l?1.f:0.f) + (fabsf(xl.y)>=thr_l?1.f:0.f)
             + (fabsf(xl.z)>=thr_l?1.f:0.f) + (fabsf(xl.w)>=thr_l?1.f:0.f);
  float dr_c = (fabsf(xr.x)>=thr_r?1.f:0.f) + (fabsf(xr.y)>=thr_r?1.f:0.f)
             + (fabsf(xr.z)>=thr_r?1.f:0.f) + (fabsf(xr.w)>=thr_r?1.f:0.f);
  float dur_l = wsum(dl_c), dur_r = wsum(dr_c);

  float nxl = __shfl_down(xl.x,1), nxr = __shfl_down(xr.x,1);
  float nyl = __shfl_down(yl.x,1), nyr = __shfl_down(yr.x,1);
  const bool last = (lane==63);
  float zl_c = ((xl.x<0.f)!=(xl.y<0.f)?1.f:0.f) + ((xl.y<0.f)!=(xl.z<0.f)?1.f:0.f)
             + ((xl.z<0.f)!=(xl.w<0.f)?1.f:0.f)
             + ((!last && ((xl.w<0.f)!=(nxl<0.f)))?1.f:0.f);
  float zr_c = ((xr.x<0.f)!=(xr.y<0.f)?1.f:0.f) + ((xr.y<0.f)!=(xr.z<0.f)?1.f:0.f)
             + ((xr.z<0.f)!=(xr.w<0.f)?1.f:0.f)
             + ((!last && ((xr.w<0.f)!=(nxr<0.f)))?1.f:0.f);
  float zc_l = wsum(zl_c), zc_r = wsum(zr_c);
  float vl_c = fabsf(yl.y-yl.x)+fabsf(yl.z-yl.y)+fabsf(yl.w-yl.z) + (last?0.f:fabsf(nyl-yl.w));
  float vr_c = fabsf(yr.y-yr.x)+fabsf(yr.z-yr.y)+fabsf(yr.w-yr.z) + (last?0.f:fabsf(nyr-yr.w));
  float vib_l = wsum(vl_c), vib_r = wsum(vr_c);

  // ---- build e/o (conjugate fold) via cross-lane reversal; write per-wave LDS
  const int par = 63-lane, pj = (64-lane)&63;
  float r0y=__shfl(xl.y,par), r0z=__shfl(xl.z,par), r0w=__shfl(xl.w,par);
  float b00=__shfl(xl.x,pj);
  float r1y=__shfl(xr.y,par), r1z=__shfl(xr.z,par), r1w=__shfl(xr.w,par);
  float b01=__shfl(xr.x,pj);
  float x00 =__shfl(xl.x,0), x0128=__shfl(xl.x,32);
  float x10 =__shfl(xr.x,0), x1128=__shfl(xr.x,32);
  if (lane < 32) {
    float4 e,o;
    e.x=xl.x+b00; o.x=xl.x-b00; e.y=xl.y+r0w; o.y=xl.y-r0w;
    e.z=xl.z+r0z; o.z=xl.z-r0z; e.w=xl.w+r0y; o.w=xl.w-r0y;
    ((float4*)sE0)[lane]=e; ((float4*)sO0)[lane]=o;
    e.x=xr.x+b01; o.x=xr.x-b01; e.y=xr.y+r1w; o.y=xr.y-r1w;
    e.z=xr.z+r1z; o.z=xr.z-r1z; e.w=xr.w+r1y; o.w=xr.w-r1y;
    ((float4*)sE1)[lane]=e; ((float4*)sO1)[lane]=o;
  }

  // ---- 6 gyro groups (3 contiguous channels each), pure wave reductions
  float gvar[6], gpk[6];
  #pragma unroll
  for (int g=0; g<6; ++g){
    const float* base = (g<2)? fp : (g<4)? sp : tp;
    const float* src  = base + ((g&1)? 2304 : 768);   // ch9*256 : ch3*256
    float4 v0 = ((const float4*)src      )[lane];
    float4 v1 = ((const float4*)(src+256))[lane];
    float4 v2 = ((const float4*)(src+512))[lane];
    float s0 = wsum(sum4(v0));
    float s1 = wsum(sum4(v1));
    float s2 = wsum(sum4(v2));
    float qt = wsum(dot4(v0)+dot4(v1)+dot4(v2));
    gpk[g]   = wmax(fmaxf(amax4(v0),fmaxf(amax4(v1),amax4(v2))));
    gvar[g]  = (qt - (s0*s0+s1*s1+s2*s2)*(1.f/256.f))*(1.f/255.f);
  }

  // ---- DFT: lane computes bins {lane, lane+64} for BOTH rows (e/o folded)
  float th = (float)lane * 0.024543692606f;  // 2*pi/256
  float c1,s1v; __sincosf(th,&s1v,&c1);
  float cA=c1, sA=s1v;        // chain for bin k=lane, value at n=1
  float cB=-s1v, sB=c1;       // bin k=lane+64: step angle th+pi/2
  float sgn = (lane&1)? -1.f : 1.f;  // (-1)^k, same for k and k+64
  float c00 = x00 + sgn*x0128, s00=0.f;   // row0 bin lane
  float c01 = c00,             s01=0.f;   // row0 bin lane+64 (same init)
  float c10 = x10 + sgn*x1128, s10=0.f;   // row1 bin lane
  float c11 = c10,             s11=0.f;   // row1 bin lane+64
  #pragma unroll 4
  for (int n=1; n<128; ++n){
    float e0=sE0[n], o0=sO0[n], e1=sE1[n], o1=sO1[n];  // wave-uniform broadcast
    c00=fmaf(e0,cA,c00); s00=fmaf(o0,sA,s00);
    c10=fmaf(e1,cA,c10); s10=fmaf(o1,sA,s10);
    c01=fmaf(e0,cB,c01); s01=fmaf(o0,sB,s01);
    c11=fmaf(e1,cB,c11); s11=fmaf(o1,sB,s11);
    float cAn=fmaf(cA,c1,-(sA*s1v)); sA=fmaf(sA,c1,cA*s1v); cA=cAn;
    float cBn=fmaf(cB,-s1v,-(sB*c1)); float sBn=fmaf(cB,c1,-(sB*s1v)); cB=cBn; sB=sBn;
  }
  float PA0=c00*c00+s00*s00, PB0=c01*c01+s01*s01;
  float PA1=c10*c10+s10*s10, PB1=c11*c11+s11*s11;
  float kf=(float)lane;
  float tot0=wsum(PA0+PB0);
  float hfs0=wsum(((lane>=60)?PA0:0.f)+PB0);
  float cw0 =wsum(kf*PA0+(kf+64.f)*PB0);
  float tot1=wsum(PA1+PB1);
  float hfs1=wsum(((lane>=60)?PA1:0.f)+PB1);
  float cw1 =wsum(kf*PA1+(kf+64.f)*PB1);
  float P1280=alt_l*alt_l, P1281=alt_r*alt_r;   // bin 128
  tot0+=P1280; hfs0+=P1280; cw0=fmaf(128.f,P1280,cw0);
  tot1+=P1281; hfs1+=P1281; cw1=fmaf(128.f,P1281,cw1);
  float hf_l=hfs0/(tot0+1e-6f), hf_r=hfs1/(tot1+1e-6f);
  float sc_l=cw0/(tot0+1e-6f)*(1.f/129.f), sc_r=cw1/(tot1+1e-6f)*(1.f/129.f);

  // ---- epilogue (wave-uniform values; lane 0 stores)
  float var_sl = fmaxf((ssq_l - ssum_l*ssum_l*(1.f/256.f))*(1.f/255.f), 0.f);
  float var_sr = fmaxf((ssq_r - ssum_r*ssum_r*(1.f/256.f))*(1.f/255.f), 0.f);
  float frms_l = sqrtf(sq_l *(1.f/256.f)), frms_r = sqrtf(sq_r *(1.f/256.f));
  float srms_l = sqrtf(ssq_l*(1.f/256.f)), srms_r = sqrtf(ssq_r*(1.f/256.f));
  float fgv_l = log1pf(gvar[0]), fgv_r = log1pf(gvar[1]);
  float sgv_l = log1pf(gvar[2]), sgv_r = log1pf(gvar[3]);
  float tgv_l = log1pf(gvar[4]), tgv_r = log1pf(gvar[5]);

  if (lane == 0) {
    float* o = out + (size_t)b*44;
    o[0]  = pk_l;  o[1]  = pk_r;
    o[2]  = spk_l; o[3]  = spk_r;
    o[4]  = log1pf(pk_l/(spk_l+1e-4f));
    o[5]  = log1pf(pk_r/(spk_r+1e-4f));
    o[6]  = hf_l;  o[7]  = hf_r;
    o[8]  = std_l; o[9]  = std_r;
    o[10] = (h1l*(1.f/128.f))/(h2l*(1.f/128.f)+1e-6f);
    o[11] = (h1r*(1.f/128.f))/(h2r*(1.f/128.f)+1e-6f);
    o[12] = vib_l*(1.f/255.f);
    o[13] = vib_r*(1.f/255.f);
    o[14] = log1pf(var_fl/(var_sl+1e-4f));
    o[15] = log1pf(var_fr/(var_sr+1e-4f));
    o[16] = sc_l;  o[17] = sc_r;
    o[18] = dur_l*(1.f/256.f);
    o[19] = dur_r*(1.f/256.f);
    o[20] = fgv_l; o[21] = fgv_r;
    o[22] = gpk[0]; o[23] = gpk[1];
    o[24] = sgv_l; o[25] = sgv_r;
    o[26] = gpk[2]; o[27] = gpk[3];
    o[28] = tgv_l; o[29] = tgv_r;
    o[30] = gpk[4]; o[31] = gpk[5];
    o[32] = fabsf(pk_l-spk_l);
    o[33] = fabsf(pk_r-spk_r);
    o[34] = fabsf(fgv_l-sgv_l);
    o[35] = fabsf(fgv_r-sgv_r);
    o[36] = log1pf(srms_l/(frms_l+1e-6f));
    o[37] = log1pf(srms_r/(frms_r+1e-6f));
    o[38] = clampf(p4l*(1.f/256.f), -10.f, 30.f);
    o[39] = clampf(p4r*(1.f/256.f), -10.f, 30.f);
    o[40] = clampf(p3l*(1.f/256.f), -10.f, 10.f);
    o[41] = clampf(p3r*(1.f/256.f), -10.f, 10.f);
    o[42] = zc_l*(1.f/255.f);
    o[43] = zc_r*(1.f/255.f);
  }
}

extern "C" void kernel_launch(void* const* d_in, const int* in_sizes, int n_in,
                              void* d_out, int out_size, void* d_ws, size_t ws_size,
                              hipStream_t stream) {
  const float* foot  = (const float*)d_in[0];
  const float* shank = (const float*)d_in[1];
  const float* thigh = (const float*)d_in[2];
  float* out = (float*)d_out;
  int B = in_sizes[0] / (12 * 256);
  biomech_kernel<<<dim3((B+3)/4), dim3(256), 0, stream>>>(foot, shank, thigh, out, B);
}

// Round 4
// 62.671 us; speedup vs baseline: 6.9079x; 1.4651x over previous
//
#include <hip/hip_runtime.h>
#include <math.h>

// BioMechFeatures: B x 12 x 256 f32 (foot, shank, thigh) -> B x 44 f32.
// Block = 256 threads (4 waves) = 8 batch elements.
// Phase 1: wave-per-batch stats (2 batches/wave, shuffle reductions only),
//          stage foot-z rows as bf16 into XOR-swizzled LDS.
// Phase 2: DFT power spectrum via mfma_f32_16x16x32_bf16 (A=16x256 samples,
//          B=trig from 256-entry LDS table), 32 MFMA/wave.
// Phase 3: 16 threads combine per-row spectral partials -> hf, sc features.

typedef __attribute__((ext_vector_type(8))) short short8;
typedef __attribute__((ext_vector_type(4))) float f32x4;

__device__ __forceinline__ float wsum(float v){
  v += __shfl_xor(v,1); v += __shfl_xor(v,2); v += __shfl_xor(v,4);
  v += __shfl_xor(v,8); v += __shfl_xor(v,16); v += __shfl_xor(v,32);
  return v;
}
__device__ __forceinline__ float wmax(float v){
  v = fmaxf(v,__shfl_xor(v,1)); v = fmaxf(v,__shfl_xor(v,2)); v = fmaxf(v,__shfl_xor(v,4));
  v = fmaxf(v,__shfl_xor(v,8)); v = fmaxf(v,__shfl_xor(v,16)); v = fmaxf(v,__shfl_xor(v,32));
  return v;
}
__device__ __forceinline__ float red16(float v){  // sum across the 16-lane (lane&15) group
  v += __shfl_xor(v,1); v += __shfl_xor(v,2); v += __shfl_xor(v,4); v += __shfl_xor(v,8);
  return v;
}
__device__ __forceinline__ float sum4(float4 v){ return (v.x+v.y)+(v.z+v.w); }
__device__ __forceinline__ float dot4(float4 v){ return (v.x*v.x+v.y*v.y)+(v.z*v.z+v.w*v.w); }
__device__ __forceinline__ float amax4(float4 v){ return fmaxf(fmaxf(fabsf(v.x),fabsf(v.y)),fmaxf(fabsf(v.z),fabsf(v.w))); }
__device__ __forceinline__ float asum4(float4 v){ return (fabsf(v.x)+fabsf(v.y))+(fabsf(v.z)+fabsf(v.w)); }
__device__ __forceinline__ float clampf(float v,float lo,float hi){ return fminf(fmaxf(v,lo),hi); }
__device__ __forceinline__ unsigned short f2bf(float f){   // RNE f32->bf16
  unsigned u = __float_as_uint(f);
  return (unsigned short)((u + 0x7FFFu + ((u>>16)&1u)) >> 16);
}

__global__ __launch_bounds__(256,4) void biomech_kernel(
    const float* __restrict__ foot, const float* __restrict__ shank,
    const float* __restrict__ thigh, float* __restrict__ out, int B)
{
  const int t    = threadIdx.x;
  const int lane = t & 63;
  const int wv   = t >> 6;

  __shared__ __align__(16) unsigned short sA[16*256];  // 8KB bf16 A, XOR-swizzled
  __shared__ unsigned short sTab[256];                 // bf16 cos(2*pi*m/256)
  __shared__ float sPart[8][16][3];                    // per-tile per-row {tot,hf,cw}
  __shared__ float sAlt[16];                           // alternating sum per row (bin 128)

  // trig table: one entry per thread
  sTab[t] = f2bf(__cosf((float)t * 0.0245436926066f)); // 2*pi/256

  // ================= Phase 1: stats (2 batches per wave) =================
  #pragma unroll
  for (int bi = 0; bi < 2; ++bi) {
    const int bl = wv*2 + bi;                          // block-local batch 0..7
    const long long b = (long long)blockIdx.x*8 + bl;
    if (b >= B) continue;
    const float* fp = foot  + (size_t)b*3072;
    const float* sp = shank + (size_t)b*3072;
    const float* tp = thigh + (size_t)b*3072;

    float4 xl = ((const float4*)(fp+ 512))[lane];
    float4 xr = ((const float4*)(fp+2048))[lane];
    float4 yl = ((const float4*)(sp+ 512))[lane];
    float4 yr = ((const float4*)(sp+2048))[lane];

    // stage foot-z rows as bf16 (rows 2bl, 2bl+1), XOR-swizzled
    {
      int r0 = 2*bl, r1 = 2*bl+1;
      unsigned lo0 = (unsigned)f2bf(xl.x) | ((unsigned)f2bf(xl.y)<<16);
      unsigned hi0 = (unsigned)f2bf(xl.z) | ((unsigned)f2bf(xl.w)<<16);
      unsigned by0 = (((unsigned)r0<<9) + ((unsigned)lane<<3)) ^ (((unsigned)(r0&7))<<4);
      *(uint2*)((char*)sA + by0) = make_uint2(lo0,hi0);
      unsigned lo1 = (unsigned)f2bf(xr.x) | ((unsigned)f2bf(xr.y)<<16);
      unsigned hi1 = (unsigned)f2bf(xr.z) | ((unsigned)f2bf(xr.w)<<16);
      unsigned by1 = (((unsigned)r1<<9) + ((unsigned)lane<<3)) ^ (((unsigned)(r1&7))<<4);
      *(uint2*)((char*)sA + by1) = make_uint2(lo1,hi1);
    }

    float pk_l  = wmax(amax4(xl)), pk_r  = wmax(amax4(xr));
    float spk_l = wmax(amax4(yl)), spk_r = wmax(amax4(yr));
    float sum_l = wsum(sum4(xl)),  sum_r = wsum(sum4(xr));
    float sq_l  = wsum(dot4(xl)),  sq_r  = wsum(dot4(xr));
    float ssum_l= wsum(sum4(yl)),  ssum_r= wsum(sum4(yr));
    float ssq_l = wsum(dot4(yl)),  ssq_r = wsum(dot4(yr));
    float al = asum4(xl), ar = asum4(xr);
    float h1l = wsum(lane<32 ? al : 0.f), h2l = wsum(lane<32 ? 0.f : al);
    float h1r = wsum(lane<32 ? ar : 0.f), h2r = wsum(lane<32 ? 0.f : ar);
    float alt_l = wsum((xl.x - xl.y) + (xl.z - xl.w));
    float alt_r = wsum((xr.x - xr.y) + (xr.z - xr.w));
    if (lane == 0) { sAlt[2*bl] = alt_l; sAlt[2*bl+1] = alt_r; }

    float mu_l = sum_l*(1.f/256.f), mu_r = sum_r*(1.f/256.f);
    float var_fl = fmaxf((sq_l - 256.f*mu_l*mu_l)*(1.f/255.f), 0.f);
    float var_fr = fmaxf((sq_r - 256.f*mu_r*mu_r)*(1.f/255.f), 0.f);
    float std_l = sqrtf(var_fl), std_r = sqrtf(var_fr);
    float inv_l = 1.f/fmaxf(std_l,1e-6f), inv_r = 1.f/fmaxf(std_r,1e-6f);

    float p3l_c=0.f, p4l_c=0.f, p3r_c=0.f, p4r_c=0.f;
    {
      float p,p2;
      p=(xl.x-mu_l)*inv_l; p2=p*p; p3l_c+=p2*p; p4l_c+=p2*p2;
      p=(xl.y-mu_l)*inv_l; p2=p*p; p3l_c+=p2*p; p4l_c+=p2*p2;
      p=(xl.z-mu_l)*inv_l; p2=p*p; p3l_c+=p2*p; p4l_c+=p2*p2;
      p=(xl.w-mu_l)*inv_l; p2=p*p; p3l_c+=p2*p; p4l_c+=p2*p2;
      p=(xr.x-mu_r)*inv_r; p2=p*p; p3r_c+=p2*p; p4r_c+=p2*p2;
      p=(xr.y-mu_r)*inv_r; p2=p*p; p3r_c+=p2*p; p4r_c+=p2*p2;
      p=(xr.z-mu_r)*inv_r; p2=p*p; p3r_c+=p2*p; p4r_c+=p2*p2;
      p=(xr.w-mu_r)*inv_r; p2=p*p; p3r_c+=p2*p; p4r_c+=p2*p2;
    }
    float p3l = wsum(p3l_c), p4l = wsum(p4l_c);
    float p3r = wsum(p3r_c), p4r = wsum(p4r_c);

    float thr_l = 0.3f*pk_l, thr_r = 0.3f*pk_r;
    float dl_c = (fabsf(xl.x)>=thr_l?1.f:0.f) + (fabsf(xl.y)>=thr_l?1.f:0.f)
               + (fabsf(xl.z)>=thr_l?1.f:0.f) + (fabsf(xl.w)>=thr_l?1.f:0.f);
    float dr_c = (fabsf(xr.x)>=thr_r?1.f:0.f) + (fabsf(xr.y)>=thr_r?1.f:0.f)
               + (fabsf(xr.z)>=thr_r?1.f:0.f) + (fabsf(xr.w)>=thr_r?1.f:0.f);
    float dur_l = wsum(dl_c), dur_r = wsum(dr_c);

    float nxl = __shfl_down(xl.x,1), nxr = __shfl_down(xr.x,1);
    float nyl = __shfl_down(yl.x,1), nyr = __shfl_down(yr.x,1);
    const bool last = (lane==63);
    float zl_c = ((xl.x<0.f)!=(xl.y<0.f)?1.f:0.f) + ((xl.y<0.f)!=(xl.z<0.f)?1.f:0.f)
               + ((xl.z<0.f)!=(xl.w<0.f)?1.f:0.f)
               + ((!last && ((xl.w<0.f)!=(nxl<0.f)))?1.f:0.f);
    float zr_c = ((xr.x<0.f)!=(xr.y<0.f)?1.f:0.f) + ((xr.y<0.f)!=(xr.z<0.f)?1.f:0.f)
               + ((xr.z<0.f)!=(xr.w<0.f)?1.f:0.f)
               + ((!last && ((xr.w<0.f)!=(nxr<0.f)))?1.f:0.f);
    float zc_l = wsum(zl_c), zc_r = wsum(zr_c);
    float vl_c = fabsf(yl.y-yl.x)+fabsf(yl.z-yl.y)+fabsf(yl.w-yl.z) + (last?0.f:fabsf(nyl-yl.w));
    float vr_c = fabsf(yr.y-yr.x)+fabsf(yr.z-yr.y)+fabsf(yr.w-yr.z) + (last?0.f:fabsf(nyr-yr.w));
    float vib_l = wsum(vl_c), vib_r = wsum(vr_c);

    float gvar[6], gpk[6];
    #pragma unroll
    for (int g=0; g<6; ++g){
      const float* base = (g<2)? fp : (g<4)? sp : tp;
      const float* src  = base + ((g&1)? 2304 : 768);
      float4 v0 = ((const float4*)src      )[lane];
      float4 v1 = ((const float4*)(src+256))[lane];
      float4 v2 = ((const float4*)(src+512))[lane];
      float s0 = wsum(sum4(v0));
      float s1 = wsum(sum4(v1));
      float s2 = wsum(sum4(v2));
      float qt = wsum(dot4(v0)+dot4(v1)+dot4(v2));
      gpk[g]   = wmax(fmaxf(amax4(v0),fmaxf(amax4(v1),amax4(v2))));
      gvar[g]  = (qt - (s0*s0+s1*s1+s2*s2)*(1.f/256.f))*(1.f/255.f);
    }

    float var_sl = fmaxf((ssq_l - ssum_l*ssum_l*(1.f/256.f))*(1.f/255.f), 0.f);
    float var_sr = fmaxf((ssq_r - ssum_r*ssum_r*(1.f/256.f))*(1.f/255.f), 0.f);
    float frms_l = sqrtf(sq_l *(1.f/256.f)), frms_r = sqrtf(sq_r *(1.f/256.f));
    float srms_l = sqrtf(ssq_l*(1.f/256.f)), srms_r = sqrtf(ssq_r*(1.f/256.f));
    float fgv_l = log1pf(gvar[0]), fgv_r = log1pf(gvar[1]);
    float sgv_l = log1pf(gvar[2]), sgv_r = log1pf(gvar[3]);
    float tgv_l = log1pf(gvar[4]), tgv_r = log1pf(gvar[5]);

    if (lane == 0) {
      float* o = out + (size_t)b*44;
      o[0]  = pk_l;  o[1]  = pk_r;
      o[2]  = spk_l; o[3]  = spk_r;
      o[4]  = log1pf(pk_l/(spk_l+1e-4f));
      o[5]  = log1pf(pk_r/(spk_r+1e-4f));
      o[8]  = std_l; o[9]  = std_r;
      o[10] = (h1l*(1.f/128.f))/(h2l*(1.f/128.f)+1e-6f);
      o[11] = (h1r*(1.f/128.f))/(h2r*(1.f/128.f)+1e-6f);
      o[12] = vib_l*(1.f/255.f);
      o[13] = vib_r*(1.f/255.f);
      o[14] = log1pf(var_fl/(var_sl+1e-4f));
      o[15] = log1pf(var_fr/(var_sr+1e-4f));
      o[18] = dur_l*(1.f/256.f);
      o[19] = dur_r*(1.f/256.f);
      o[20] = fgv_l; o[21] = fgv_r;
      o[22] = gpk[0]; o[23] = gpk[1];
      o[24] = sgv_l; o[25] = sgv_r;
      o[26] = gpk[2]; o[27] = gpk[3];
      o[28] = tgv_l; o[29] = tgv_r;
      o[30] = gpk[4]; o[31] = gpk[5];
      o[32] = fabsf(pk_l-spk_l);
      o[33] = fabsf(pk_r-spk_r);
      o[34] = fabsf(fgv_l-sgv_l);
      o[35] = fabsf(fgv_r-sgv_r);
      o[36] = log1pf(srms_l/(frms_l+1e-6f));
      o[37] = log1pf(srms_r/(frms_r+1e-6f));
      o[38] = clampf(p4l*(1.f/256.f), -10.f, 30.f);
      o[39] = clampf(p4r*(1.f/256.f), -10.f, 30.f);
      o[40] = clampf(p3l*(1.f/256.f), -10.f, 10.f);
      o[41] = clampf(p3r*(1.f/256.f), -10.f, 10.f);
      o[42] = zc_l*(1.f/255.f);
      o[43] = zc_r*(1.f/255.f);
    }
  }
  __syncthreads();

  // ================= Phase 2: DFT via MFMA =================
  // Wave wv handles bin tiles T0=2wv, T1=2wv+1 (16 bins each, bins 0..127).
  {
    const int col = lane & 15;        // bin-within-tile AND A-row index
    const int g   = lane >> 4;        // 4 k-groups of 8
    const int T0  = wv*2, T1 = T0+1;
    const int nb0 = T0*16 + col, nb1 = nb0 + 16;
    f32x4 ac0={0,0,0,0}, as0={0,0,0,0}, ac1={0,0,0,0}, as1={0,0,0,0};

    #pragma unroll 4
    for (int s = 0; s < 8; ++s) {
      // A fragment: row=col(lane&15), samples n0..n0+7, n0 = g*8 + 32s
      unsigned abyte = (((unsigned)col<<9) + ((unsigned)g<<4) + ((unsigned)s<<6))
                       ^ (((unsigned)(col&7))<<4);
      short8 af = *(const short8*)((const char*)sA + abyte);
      // B fragments from trig table: B[n][bin] = cos(2*pi*n*bin/256); sin = cos(idx-64)
      int n0 = (g<<3) + (s<<5);
      short8 bc0, bs0, bc1, bs1;
      int m0 = (n0*nb0) & 255, m1 = (n0*nb1) & 255;
      #pragma unroll
      for (int j=0;j<8;++j){
        bc0[j] = (short)sTab[m0]; bs0[j] = (short)sTab[(m0+192)&255];
        bc1[j] = (short)sTab[m1]; bs1[j] = (short)sTab[(m1+192)&255];
        m0 = (m0 + nb0) & 255;    m1 = (m1 + nb1) & 255;
      }
      ac0 = __builtin_amdgcn_mfma_f32_16x16x32_bf16(af, bc0, ac0, 0,0,0);
      as0 = __builtin_amdgcn_mfma_f32_16x16x32_bf16(af, bs0, as0, 0,0,0);
      ac1 = __builtin_amdgcn_mfma_f32_16x16x32_bf16(af, bc1, ac1, 0,0,0);
      as1 = __builtin_amdgcn_mfma_f32_16x16x32_bf16(af, bs1, as1, 0,0,0);
    }

    // Reduce per row across the tile's 16 bins. D layout: col=lane&15, row=g*4+q.
    float kf0 = (float)nb0, kf1 = (float)nb1;
    #pragma unroll
    for (int q=0; q<4; ++q){
      int row = (g<<2) + q;
      float P0 = ac0[q]*ac0[q] + as0[q]*as0[q];
      float P1 = ac1[q]*ac1[q] + as1[q]*as1[q];
      float tp0 = red16(P0), tp1 = red16(P1);
      float cp0 = red16(kf0*P0), cp1 = red16(kf1*P1);
      float hp0, hp1;
      if (T0 == 3)      hp0 = red16(col >= 12 ? P0 : 0.f);   // bins 48..63: >=60
      else if (T0 >= 4) hp0 = tp0; else hp0 = 0.f;
      if (T1 == 3)      hp1 = red16(col >= 12 ? P1 : 0.f);
      else if (T1 >= 4) hp1 = tp1; else hp1 = 0.f;
      if (col == 0) {
        sPart[T0][row][0]=tp0; sPart[T0][row][1]=hp0; sPart[T0][row][2]=cp0;
        sPart[T1][row][0]=tp1; sPart[T1][row][1]=hp1; sPart[T1][row][2]=cp1;
      }
    }
  }
  __syncthreads();

  // ================= Phase 3: combine spectral partials =================
  if (t < 16) {
    const int row = t;
    const long long b = (long long)blockIdx.x*8 + (row>>1);
    if (b < B) {
      float tot=0.f, hp=0.f, cw=0.f;
      #pragma unroll
      for (int tl=0; tl<8; ++tl){
        tot += sPart[tl][row][0];
        hp  += sPart[tl][row][1];
        cw  += sPart[tl][row][2];
      }
      float a = sAlt[row], P128 = a*a;
      tot += P128; hp += P128; cw = fmaf(128.f, P128, cw);
      int ch = row & 1;
      float* o = out + (size_t)b*44;
      o[6+ch]  = hp/(tot+1e-6f);
      o[16+ch] = cw/(tot+1e-6f)*(1.f/129.f);
    }
  }
}

extern "C" void kernel_launch(void* const* d_in, const int* in_sizes, int n_in,
                              void* d_out, int out_size, void* d_ws, size_t ws_size,
                              hipStream_t stream) {
  const float* foot  = (const float*)d_in[0];
  const float* shank = (const float*)d_in[1];
  const float* thigh = (const float*)d_in[2];
  float* out = (float*)d_out;
  int B = in_sizes[0] / (12 * 256);
  biomech_kernel<<<dim3((B+7)/8), dim3(256), 0, stream>>>(foot, shank, thigh, out, B);
}